// Round 3
// baseline (68.256 us; speedup 1.0000x reference)
//
#include <hip/hip_runtime.h>
#include <hip/hip_fp16.h>

#define N 8192
#define D 128
#define MARGIN 0.3f

typedef __fp16 half_t;
typedef __attribute__((ext_vector_type(8))) __fp16 half8;
typedef __attribute__((ext_vector_type(4))) float f32x4;

#define AS1C(p) ((const __attribute__((address_space(1))) void*)(p))
#define AS3(p)  ((__attribute__((address_space(3))) void*)(p))

// ---------------- prep: fp32 -> fp16, exact fp32 norms, zero accumulators ----
__global__ void triplet_prep(const float* __restrict__ x,
                             half_t* __restrict__ xh,
                             float* __restrict__ norms,
                             float* __restrict__ gacc) {
    const int gt = blockIdx.x * 256 + threadIdx.x;
    if (gt < 3) gacc[gt] = 0.f;          // [0]=sum [1]=count [2]=ticket
    const int row  = gt >> 6;            // one wave per row
    const int lane = gt & 63;
    const float* rp = x + (size_t)row * D;
    float a0 = rp[lane], a1 = rp[lane + 64];
    xh[(size_t)row * D + lane]      = (half_t)a0;
    xh[(size_t)row * D + lane + 64] = (half_t)a1;
    float s = fmaf(a0, a0, a1 * a1);
#pragma unroll
    for (int o = 32; o > 0; o >>= 1) s += __shfl_xor(s, o);
    if (lane == 0) norms[row] = s;
}

// ---------------- main: fused fp16-MFMA Gram + masked row max/min ------------
// grid: 64 row-strips x 8 j-chunks = 512 blocks (2/CU). 4 waves (2x2), 128x128 tile.
// A in registers; B double-buffered (static even/odd) via global_load_lds.
struct TState {
    float mpos[16];
    float mneg[16];
};

__device__ __forceinline__ void tile_body(
    const half_t* __restrict__ Scur, half_t* __restrict__ Snxt,
    bool dopf, int pfjt, int jt,
    const half_t* __restrict__ xh,
    int jchunk0, int irow0, int sgoff, int sldst,
    int wr, int wc, int lrow, int lcol,
    const int* __restrict__ Ljs, const float* __restrict__ Njs,
    const half8 (&af)[4][4], const int (&li)[16], const int (&rowB)[4],
    const int (&physk)[4], TState& st)
{
    // issue next-tile prefetch first (in flight across this whole body)
    if (dopf) {
        const int nb = jchunk0 + pfjt * 128;
#pragma unroll
        for (int it = 0; it < 8; ++it)
            __builtin_amdgcn_global_load_lds(AS1C(xh + (size_t)(nb + it * 16) * D + sgoff),
                                             AS3(Snxt + it * 2048 + sldst), 16, 0, 0);
    }

    const int jbase = jchunk0 + jt * 128;
    int lj[4]; float njv[4];
#pragma unroll
    for (int fj = 0; fj < 4; ++fj) {
        int idx = jt * 128 + wc * 64 + fj * 16 + lcol;
        lj[fj]  = Ljs[idx];
        njv[fj] = Njs[idx];
    }

    f32x4 acc[4][4];
#pragma unroll
    for (int fi = 0; fi < 4; ++fi)
#pragma unroll
        for (int fj = 0; fj < 4; ++fj)
            acc[fi][fj] = (f32x4){0.f, 0.f, 0.f, 0.f};

    __builtin_amdgcn_s_setprio(1);
#pragma unroll
    for (int ks = 0; ks < 4; ++ks) {
        half8 bv[4];
#pragma unroll
        for (int fj = 0; fj < 4; ++fj)
            bv[fj] = *(const half8*)(Scur + rowB[fj] + physk[ks]);
#pragma unroll
        for (int fi = 0; fi < 4; ++fi)
#pragma unroll
            for (int fj = 0; fj < 4; ++fj)
                acc[fi][fj] = __builtin_amdgcn_mfma_f32_16x16x32_f16(
                    af[fi][ks], bv[fj], acc[fi][fj], 0, 0, 0);
    }
    __builtin_amdgcn_s_setprio(0);

    // diagonal tile: poison self-distance accumulators so they never win the max
    if (jbase == irow0) {
        bool dl = (wr == wc) && (lrow == (lcol >> 2));
        int  dr = lcol & 3;
#pragma unroll
        for (int f = 0; f < 4; ++f)
#pragma unroll
            for (int rg = 0; rg < 4; ++rg)
                acc[f][f][rg] = (dl && (rg == dr)) ? 1e30f : acc[f][f][rg];
    }

    // lean epilogue: cand = n_j - 2 g_ij ; masked running max/min
#pragma unroll
    for (int fi = 0; fi < 4; ++fi)
#pragma unroll
        for (int fj = 0; fj < 4; ++fj)
#pragma unroll
            for (int rg = 0; rg < 4; ++rg) {
                float cand = fmaf(-2.f, acc[fi][fj][rg], njv[fj]);
                int r = fi * 4 + rg;
                bool same = (li[r] == lj[fj]);
                st.mpos[r] = same ? fmaxf(st.mpos[r], cand) : st.mpos[r];
                st.mneg[r] = same ? st.mneg[r] : fminf(st.mneg[r], cand);
            }

    asm volatile("s_waitcnt vmcnt(0)" ::: "memory");
    __builtin_amdgcn_s_barrier();
    __builtin_amdgcn_sched_barrier(0);
}

__launch_bounds__(256, 2)
__global__ void triplet_main(const half_t* __restrict__ xh,
                             const float* __restrict__ norms,
                             const int* __restrict__ labels,
                             float* __restrict__ ppos,
                             float* __restrict__ pneg) {
    __shared__ __align__(16) half_t S0[128 * D];   // 32 KiB
    __shared__ __align__(16) half_t S1[128 * D];   // 32 KiB
    __shared__ __align__(16) int    Ljs[1024];     // 4 KiB
    __shared__ __align__(16) float  Njs[1024];     // 4 KiB

    const int bx    = blockIdx.x;
    const int strip = bx >> 3;
    const int chunk = bx & 7;
    const int tid   = threadIdx.x;
    const int lane  = tid & 63;
    const int w     = tid >> 6;
    const int wr    = w >> 1;
    const int wc    = w & 1;
    const int lrow  = lane >> 4;
    const int lcol  = lane & 15;
    const int irow0 = strip * 128;
    const int jchunk0 = chunk * 1024;

    // staging constants: LDS row r slot s holds global slot s^(r&7)
    const int ssl   = (tid & 15) ^ ((tid >> 4) & 7);
    const int sgoff = (tid >> 4) * D + ssl * 8;
    const int sldst = tid * 8;

    const int ibase = irow0 + wr * 64 + lrow * 4;
    int li[16];
#pragma unroll
    for (int fi = 0; fi < 4; ++fi)
#pragma unroll
        for (int rg = 0; rg < 4; ++rg)
            li[fi * 4 + rg] = labels[ibase + fi * 16 + rg];

    // ---- prologue: A -> S0, labels/norms chunk -> LDS, B(tile0) -> S1 ----
#pragma unroll
    for (int it = 0; it < 8; ++it)
        __builtin_amdgcn_global_load_lds(AS1C(xh + (size_t)(irow0 + it * 16) * D + sgoff),
                                         AS3(&S0[it * 2048 + sldst]), 16, 0, 0);
    __builtin_amdgcn_global_load_lds(AS1C(labels + jchunk0 + tid * 4), AS3(&Ljs[tid * 4]), 16, 0, 0);
    __builtin_amdgcn_global_load_lds(AS1C(norms  + jchunk0 + tid * 4), AS3(&Njs[tid * 4]), 16, 0, 0);
#pragma unroll
    for (int it = 0; it < 8; ++it)
        __builtin_amdgcn_global_load_lds(AS1C(xh + (size_t)(jchunk0 + it * 16) * D + sgoff),
                                         AS3(&S1[it * 2048 + sldst]), 16, 0, 0);
    asm volatile("s_waitcnt vmcnt(0)" ::: "memory");
    __builtin_amdgcn_s_barrier();
    __builtin_amdgcn_sched_barrier(0);

    // ---- A fragments to registers (S0 then recycled as B buffer) ----
    int physk[4];
#pragma unroll
    for (int ks = 0; ks < 4; ++ks) physk[ks] = ((ks * 4 + lrow) ^ (lcol & 7)) * 8;
    half8 af[4][4];
#pragma unroll
    for (int fi = 0; fi < 4; ++fi) {
        const half_t* ap = &S0[(wr * 64 + fi * 16 + lcol) * D];
#pragma unroll
        for (int ks = 0; ks < 4; ++ks)
            af[fi][ks] = *(const half8*)(ap + physk[ks]);
    }
    asm volatile("s_waitcnt lgkmcnt(0)" ::: "memory");
    __builtin_amdgcn_sched_barrier(0);
    __builtin_amdgcn_s_barrier();
    __builtin_amdgcn_sched_barrier(0);

    int rowB[4];
#pragma unroll
    for (int f4 = 0; f4 < 4; ++f4) rowB[f4] = (wc * 64 + f4 * 16 + lcol) * D;

    TState st;
#pragma unroll
    for (int r = 0; r < 16; ++r) { st.mpos[r] = -1e38f; st.mneg[r] = 1e38f; }

    // ---- main loop: 4 x (compute S1 / prefetch S0 ; compute S0 / prefetch S1) ----
    for (int k = 0; k < 4; ++k) {
        tile_body(S1, S0, true,    2 * k + 1, 2 * k,     xh, jchunk0, irow0, sgoff, sldst,
                  wr, wc, lrow, lcol, Ljs, Njs, af, li, rowB, physk, st);
        tile_body(S0, S1, (k < 3), 2 * k + 2, 2 * k + 1, xh, jchunk0, irow0, sgoff, sldst,
                  wr, wc, lrow, lcol, Ljs, Njs, af, li, rowB, physk, st);
    }

    // reduce across the 16 col-lanes (C cols live on lcol)
#pragma unroll
    for (int o = 1; o < 16; o <<= 1) {
#pragma unroll
        for (int r = 0; r < 16; ++r) {
            st.mpos[r] = fmaxf(st.mpos[r], __shfl_xor(st.mpos[r], o));
            st.mneg[r] = fminf(st.mneg[r], __shfl_xor(st.mneg[r], o));
        }
    }
    if (lcol == 0) {
        const int slot = chunk * 2 + wc;   // 16 partial slots per row
#pragma unroll
        for (int fi = 0; fi < 4; ++fi)
#pragma unroll
            for (int rg = 0; rg < 4; ++rg) {
                int rgrow = ibase + fi * 16 + rg;
                ppos[(size_t)rgrow * 16 + slot] = st.mpos[fi * 4 + rg];
                pneg[(size_t)rgrow * 16 + slot] = st.mneg[fi * 4 + rg];
            }
    }
}

// ---------------- finalize rows + global mean (last-block ticket) ------------
__global__ void triplet_reduce(const float* __restrict__ ppos,
                               const float* __restrict__ pneg,
                               const float* __restrict__ norms,
                               float* __restrict__ gacc,
                               float* __restrict__ out) {
    __shared__ float ss[256];
    __shared__ float sc[256];
    const int tid = threadIdx.x;
    const int r   = blockIdx.x * 256 + tid;
    float mp = -1e38f, mn = 1e38f;
    const f32x4* pp = (const f32x4*)(ppos + (size_t)r * 16);
    const f32x4* pn = (const f32x4*)(pneg + (size_t)r * 16);
#pragma unroll
    for (int s4 = 0; s4 < 4; ++s4) {
        f32x4 a = pp[s4], b = pn[s4];
#pragma unroll
        for (int e = 0; e < 4; ++e) { mp = fmaxf(mp, a[e]); mn = fminf(mn, b[e]); }
    }
    float ni = norms[r];
    bool valid = (mp > -1e37f) && (mn < 1e37f);
    float hp = sqrtf(fmaxf(ni + mp, 0.f));
    float hn = sqrtf(fmaxf(ni + mn, 0.f));
    float pr = fmaxf(hp - hn + MARGIN, 0.f);
    ss[tid] = valid ? pr : 0.f;
    sc[tid] = valid ? 1.f : 0.f;
    __syncthreads();
    for (int o = 128; o > 0; o >>= 1) {
        if (tid < o) { ss[tid] += ss[tid + o]; sc[tid] += sc[tid + o]; }
        __syncthreads();
    }
    if (tid == 0) {
        atomicAdd(&gacc[0], ss[0]);
        atomicAdd(&gacc[1], sc[0]);
        __threadfence();
        unsigned* ticket = (unsigned*)(gacc + 2);
        unsigned old = atomicAdd(ticket, 1u);
        if (old == gridDim.x - 1) {
            float s = atomicAdd(&gacc[0], 0.f);
            float c = atomicAdd(&gacc[1], 0.f);
            out[0] = (c > 0.f) ? (s / c) : 0.f;
        }
    }
}

// -----------------------------------------------------------------------------
extern "C" void kernel_launch(void* const* d_in, const int* in_sizes, int n_in,
                              void* d_out, int out_size, void* d_ws, size_t ws_size,
                              hipStream_t stream) {
    const float* x      = (const float*)d_in[0];
    const int*   labels = (const int*)d_in[1];
    float*       out    = (float*)d_out;

    // ws layout: xh (2 MiB) | norms (32 KiB) | ppos (512 KiB) | pneg (512 KiB) | gacc (12 B)
    char*   ws    = (char*)d_ws;
    half_t* xh    = (half_t*)ws;
    float*  norms = (float*)(ws + (size_t)N * D * sizeof(half_t));
    float*  ppos  = norms + N;
    float*  pneg  = ppos + (size_t)N * 16;
    float*  gacc  = pneg + (size_t)N * 16;

    triplet_prep  <<<N / 4,   256, 0, stream>>>(x, xh, norms, gacc);
    triplet_main  <<<512,     256, 0, stream>>>(xh, norms, labels, ppos, pneg);
    triplet_reduce<<<N / 256, 256, 0, stream>>>(ppos, pneg, norms, gacc, out);
}

// Round 4
// 55.065 us; speedup vs baseline: 1.2396x; 1.2396x over previous
//
#include <hip/hip_runtime.h>
#include <hip/hip_fp16.h>

#define N 8192
#define D 128
#define MARGIN 0.3f

typedef __fp16 half_t;
typedef __attribute__((ext_vector_type(8))) __fp16 half8;
typedef __attribute__((ext_vector_type(4))) float f32x4;

// ---------------- prep: fp32 -> fp16, exact fp32 norms, zero accumulators ----
__global__ void triplet_prep(const float* __restrict__ x,
                             half_t* __restrict__ xh,
                             float* __restrict__ norms,
                             float* __restrict__ gacc) {
    const int gt = blockIdx.x * 256 + threadIdx.x;
    if (gt < 3) gacc[gt] = 0.f;          // [0]=sum [1]=count [2]=ticket
    const int row  = gt >> 6;            // one wave per row
    const int lane = gt & 63;
    const float* rp = x + (size_t)row * D;
    float a0 = rp[lane], a1 = rp[lane + 64];
    xh[(size_t)row * D + lane]      = (half_t)a0;
    xh[(size_t)row * D + lane + 64] = (half_t)a1;
    float s = fmaf(a0, a0, a1 * a1);
#pragma unroll
    for (int o = 32; o > 0; o >>= 1) s += __shfl_xor(s, o);
    if (lane == 0) norms[row] = s;
}

// ---------------- main: barrier-free register GEMM over L2 -------------------
// 2048 independent waves (512 blocks x 4). wave = rowgroup (64 rows) x chunk (512 cols).
// A frags in registers; B frags loaded global->reg with 3-deep rotating prefetch.

#define PF(BN, LJN, NJN, SN) {                                          \
    const int jn = colbase + (SN) * 16 + lcol;                          \
    const half_t* bp = xh + (size_t)jn * D + lrow * 8;                  \
    BN[0] = *(const half8*)bp;                                          \
    BN[1] = *(const half8*)(bp + 32);                                   \
    BN[2] = *(const half8*)(bp + 64);                                   \
    BN[3] = *(const half8*)(bp + 96);                                   \
    LJN = labels[jn];                                                   \
    NJN = norms[jn];                                                    \
}

#define POISON(ACC) {                                                   \
    _Pragma("unroll")                                                   \
    for (int rg = 0; rg < 4; ++rg)                                      \
        ACC[rg] = (diagl && rg == drg) ? 1e30f : ACC[rg];               \
}

#define EPI(ACC, FI, LJC, NJC) {                                        \
    _Pragma("unroll")                                                   \
    for (int rg = 0; rg < 4; ++rg) {                                    \
        float c = fmaf(-2.f, ACC[rg], (NJC));                           \
        bool same = (li[(FI) * 4 + rg] == (LJC));                       \
        mpos[(FI)*4+rg] = same ? fmaxf(mpos[(FI)*4+rg], c) : mpos[(FI)*4+rg]; \
        mneg[(FI)*4+rg] = same ? mneg[(FI)*4+rg] : fminf(mneg[(FI)*4+rg], c); \
    }                                                                   \
}

#define COMP(BC, LJC, NJC, S) {                                         \
    f32x4 a0 = {0,0,0,0}, a1 = {0,0,0,0}, a2 = {0,0,0,0}, a3 = {0,0,0,0}; \
    __builtin_amdgcn_s_setprio(1);                                      \
    _Pragma("unroll")                                                   \
    for (int ks = 0; ks < 4; ++ks) {                                    \
        a0 = __builtin_amdgcn_mfma_f32_16x16x32_f16(af[0][ks], BC[ks], a0, 0, 0, 0); \
        a1 = __builtin_amdgcn_mfma_f32_16x16x32_f16(af[1][ks], BC[ks], a1, 0, 0, 0); \
        a2 = __builtin_amdgcn_mfma_f32_16x16x32_f16(af[2][ks], BC[ks], a2, 0, 0, 0); \
        a3 = __builtin_amdgcn_mfma_f32_16x16x32_f16(af[3][ks], BC[ks], a3, 0, 0, 0); \
    }                                                                   \
    __builtin_amdgcn_s_setprio(0);                                      \
    const int dj = colbase + (S) * 16 - rowbase;                        \
    if (dj == 0)       POISON(a0)                                       \
    else if (dj == 16) POISON(a1)                                       \
    else if (dj == 32) POISON(a2)                                       \
    else if (dj == 48) POISON(a3)                                       \
    EPI(a0, 0, LJC, NJC)                                                \
    EPI(a1, 1, LJC, NJC)                                                \
    EPI(a2, 2, LJC, NJC)                                                \
    EPI(a3, 3, LJC, NJC)                                                \
}

__launch_bounds__(256, 2)
__global__ void triplet_main(const half_t* __restrict__ xh,
                             const float* __restrict__ norms,
                             const int* __restrict__ labels,
                             float* __restrict__ ppos,
                             float* __restrict__ pneg) {
    const int tid   = threadIdx.x;
    const int lane  = tid & 63;
    const int gw    = blockIdx.x * 4 + (tid >> 6);  // 0..2047
    const int rowg  = gw >> 4;                      // 0..127
    const int chunk = gw & 15;                      // 0..15
    const int lrow  = lane >> 4;                    // 0..3 (k-slot group / C row-group)
    const int lcol  = lane & 15;                    // 0..15 (A/B row, C col)
    const int rowbase = rowg * 64;
    const int colbase = chunk * 512;
    const bool diagl = (lrow == (lcol >> 2));
    const int  drg   = lcol & 3;

    // A fragments: row = rowbase + fi*16 + lcol, k = ks*32 + lrow*8
    half8 af[4][4];
#pragma unroll
    for (int fi = 0; fi < 4; ++fi) {
        const half_t* ap = xh + (size_t)(rowbase + fi * 16 + lcol) * D + lrow * 8;
#pragma unroll
        for (int ks = 0; ks < 4; ++ks)
            af[fi][ks] = *(const half8*)(ap + ks * 32);
    }

    // owned C-rows: rowbase + fi*16 + lrow*4 + rg
    const int ibase = rowbase + lrow * 4;
    int li[16];
#pragma unroll
    for (int fi = 0; fi < 4; ++fi)
#pragma unroll
        for (int rg = 0; rg < 4; ++rg)
            li[fi * 4 + rg] = labels[ibase + fi * 16 + rg];

    float mpos[16], mneg[16];
#pragma unroll
    for (int r = 0; r < 16; ++r) { mpos[r] = -1e38f; mneg[r] = 1e38f; }

    // 32 sub-steps of 16 cols, 3-deep rotating register prefetch, no barriers
    half8 b0[4], b1[4], b2[4];
    int lj0, lj1, lj2; float nj0, nj1, nj2;
    PF(b0, lj0, nj0, 0)
    PF(b1, lj1, nj1, 1)
    for (int s = 0; s < 30; s += 3) {
        PF(b2, lj2, nj2, s + 2)
        COMP(b0, lj0, nj0, s)
        PF(b0, lj0, nj0, s + 3)
        COMP(b1, lj1, nj1, s + 1)
        PF(b1, lj1, nj1, s + 4)
        COMP(b2, lj2, nj2, s + 2)
    }
    COMP(b0, lj0, nj0, 30)
    COMP(b1, lj1, nj1, 31)

    // reduce across the 16 col-lanes (C cols live on lcol)
#pragma unroll
    for (int o = 1; o < 16; o <<= 1) {
#pragma unroll
        for (int r = 0; r < 16; ++r) {
            mpos[r] = fmaxf(mpos[r], __shfl_xor(mpos[r], o));
            mneg[r] = fminf(mneg[r], __shfl_xor(mneg[r], o));
        }
    }
    if (lcol == 0) {
#pragma unroll
        for (int fi = 0; fi < 4; ++fi)
#pragma unroll
            for (int rg = 0; rg < 4; ++rg) {
                int row = ibase + fi * 16 + rg;
                ppos[(size_t)row * 16 + chunk] = mpos[fi * 4 + rg];
                pneg[(size_t)row * 16 + chunk] = mneg[fi * 4 + rg];
            }
    }
}

// ---------------- finalize rows + global mean (last-block ticket) ------------
__global__ void triplet_reduce(const float* __restrict__ ppos,
                               const float* __restrict__ pneg,
                               const float* __restrict__ norms,
                               float* __restrict__ gacc,
                               float* __restrict__ out) {
    __shared__ float ss[256];
    __shared__ float sc[256];
    const int tid = threadIdx.x;
    const int r   = blockIdx.x * 256 + tid;
    float mp = -1e38f, mn = 1e38f;
    const f32x4* pp = (const f32x4*)(ppos + (size_t)r * 16);
    const f32x4* pn = (const f32x4*)(pneg + (size_t)r * 16);
#pragma unroll
    for (int s4 = 0; s4 < 4; ++s4) {
        f32x4 a = pp[s4], b = pn[s4];
#pragma unroll
        for (int e = 0; e < 4; ++e) { mp = fmaxf(mp, a[e]); mn = fminf(mn, b[e]); }
    }
    float ni = norms[r];
    bool valid = (mp > -1e37f) && (mn < 1e37f);
    float hp = sqrtf(fmaxf(ni + mp, 0.f));
    float hn = sqrtf(fmaxf(ni + mn, 0.f));
    float pr = fmaxf(hp - hn + MARGIN, 0.f);
    ss[tid] = valid ? pr : 0.f;
    sc[tid] = valid ? 1.f : 0.f;
    __syncthreads();
    for (int o = 128; o > 0; o >>= 1) {
        if (tid < o) { ss[tid] += ss[tid + o]; sc[tid] += sc[tid + o]; }
        __syncthreads();
    }
    if (tid == 0) {
        atomicAdd(&gacc[0], ss[0]);
        atomicAdd(&gacc[1], sc[0]);
        __threadfence();
        unsigned* ticket = (unsigned*)(gacc + 2);
        unsigned old = atomicAdd(ticket, 1u);
        if (old == gridDim.x - 1) {
            float s = atomicAdd(&gacc[0], 0.f);
            float c = atomicAdd(&gacc[1], 0.f);
            out[0] = (c > 0.f) ? (s / c) : 0.f;
        }
    }
}

// -----------------------------------------------------------------------------
extern "C" void kernel_launch(void* const* d_in, const int* in_sizes, int n_in,
                              void* d_out, int out_size, void* d_ws, size_t ws_size,
                              hipStream_t stream) {
    const float* x      = (const float*)d_in[0];
    const int*   labels = (const int*)d_in[1];
    float*       out    = (float*)d_out;

    // ws layout: xh (2 MiB) | norms (32 KiB) | ppos (512 KiB) | pneg (512 KiB) | gacc (12 B)
    char*   ws    = (char*)d_ws;
    half_t* xh    = (half_t*)ws;
    float*  norms = (float*)(ws + (size_t)N * D * sizeof(half_t));
    float*  ppos  = norms + N;
    float*  pneg  = ppos + (size_t)N * 16;
    float*  gacc  = pneg + (size_t)N * 16;

    triplet_prep  <<<N / 4,   256, 0, stream>>>(x, xh, norms, gacc);
    triplet_main  <<<512,     256, 0, stream>>>(xh, norms, labels, ppos, pneg);
    triplet_reduce<<<N / 256, 256, 0, stream>>>(ppos, pneg, norms, gacc, out);
}